// Round 8
// baseline (569.761 us; speedup 1.0000x reference)
//
#include <hip/hip_runtime.h>

typedef __attribute__((ext_vector_type(8))) short short8;
typedef __attribute__((ext_vector_type(4))) float f32x4;

static constexpr int NN = 100000;
static constexpr int NE = 1600000;
static constexpr int DD = 128;
static constexpr int NBUCK = 196;     // 512 nodes per bucket (dst >> 9)
static constexpr int CAP = 9216;      // mean 8192 + ~11 sigma

// ws layout in 4-byte words
static constexpr int OFF_GCUR = 0;         // 256
static constexpr int OFF_OFFS = 512;       // NN+1
static constexpr int OFF_INV  = 100516;    // NN
static constexpr int OFF_WT   = 200520;    // 3*8*128*32 bf16 = 49152 words
static constexpr int OFF_SS   = 249680;    // NE
static constexpr int OFF_HB   = 1849680;   // NN*64 (h buffer A, bf16)
static constexpr int OFF_HC   = 8249680;   // NN*64 (h buffer B, bf16; ebuf aliases)

__device__ inline ushort f2b(float f) {
  uint u = __builtin_bit_cast(uint, f);
  uint r = (u + 0x7fffu + ((u >> 16) & 1u)) >> 16;
  return (ushort)r;
}
__device__ inline float b2f(ushort b) {
  uint u = ((uint)b) << 16;
  return __builtin_bit_cast(float, u);
}

// Fused pre-pass: blocks [0,12500) x->bf16, [12500,12884) weight repack, [12884] zero gcur
__global__ __launch_bounds__(256) void k_pre(const float* __restrict__ x,
                                             const float* __restrict__ Ws,
                                             const float* __restrict__ Wn,
                                             ushort* __restrict__ hb,
                                             ushort* __restrict__ WtP,
                                             int* __restrict__ gcur) {
  int b = blockIdx.x, t = threadIdx.x;
  if (b < 12500) {
    int i = b * 256 + t;               // < 3,200,000 = NN*32
    float4 v = *(const float4*)(x + (size_t)i * 4);
    uint2 p;
    p.x = (uint)f2b(v.x) | ((uint)f2b(v.y) << 16);
    p.y = (uint)f2b(v.z) | ((uint)f2b(v.w) << 16);
    *(uint2*)(hb + (size_t)i * 4) = p;
  } else if (b < 12884) {
    // WtP[((l*8+kt)*128+col)*32 + kg*8 + j] = W[l][kt*32+kg*8+j][col]
    int i = (b - 12500) * 256 + t;     // < 98304 = 3*8*128*32
    int j = i & 7;
    int kg = (i >> 3) & 3;
    int col = (i >> 5) & 127;
    int kt = (i >> 12) & 7;
    int l = i >> 15;
    int k = kt * 32 + kg * 8 + j;
    float v = (k < 128) ? Ws[((size_t)l * 128 + k) * 128 + col]
                        : Wn[((size_t)l * 128 + (k - 128)) * 128 + col];
    WtP[i] = f2b(v);
  } else {
    gcur[t] = 0;
  }
}

// Pass 1: bucket edges by dst>>9 into fixed-stride regions of ebuf
__global__ __launch_bounds__(256) void k_bucket(const int* __restrict__ src,
                                                const int* __restrict__ dst,
                                                int* __restrict__ gcur,
                                                int2* __restrict__ ebuf) {
  __shared__ int cnt[NBUCK], base[NBUCK];
  int t = threadIdx.x;
  int b0 = blockIdx.x * 4096;
  if (t < NBUCK) cnt[t] = 0;
  __syncthreads();
  int dv[16], pv[16];
#pragma unroll
  for (int j = 0; j < 16; ++j) {
    int idx = b0 + j * 256 + t;
    if (idx < NE) {
      int d = dst[idx];
      dv[j] = d;
      pv[j] = atomicAdd(&cnt[d >> 9], 1);
    } else dv[j] = -1;
  }
  __syncthreads();
  if (t < NBUCK) base[t] = atomicAdd(&gcur[t], cnt[t]);
  __syncthreads();
#pragma unroll
  for (int j = 0; j < 16; ++j) {
    if (dv[j] >= 0) {
      int idx = b0 + j * 256 + t;
      int b = dv[j] >> 9;
      int2 pr; pr.x = src[idx]; pr.y = dv[j];
      ebuf[(size_t)b * CAP + base[b] + pv[j]] = pr;
    }
  }
}

// Pass 2 (fused, inline bucket-scan): hist -> offs/inv -> LDS counting sort -> streamed ss
__global__ __launch_bounds__(256) void k_sort(const int2* __restrict__ ebuf,
                                              const int* __restrict__ gcur,
                                              int* __restrict__ offs,
                                              float* __restrict__ inv,
                                              int* __restrict__ ss) {
  __shared__ int cnt[512];
  __shared__ int sbase[512];
  __shared__ int scan[256];
  __shared__ int sarr[CAP];
  int b = blockIdx.x, t = threadIdx.x;
  // inline exclusive scan of gcur over all buckets
  int gv = (t < NBUCK) ? gcur[t] : 0;
  scan[t] = gv;
  __syncthreads();
  for (int off = 1; off < 256; off <<= 1) {
    int u = (t >= off) ? scan[t - off] : 0;
    __syncthreads();
    scan[t] += u;
    __syncthreads();
  }
  int nB = gcur[b];
  int base0 = scan[b] - nB;   // exclusive prefix for this bucket
  int n = nB;
  cnt[t] = 0; cnt[t + 256] = 0;
  __syncthreads();            // also protects scan[] reuse below
  const int2* eb = ebuf + (size_t)b * CAP;
  for (int i = t; i < n; i += 256) atomicAdd(&cnt[eb[i].y & 511], 1);
  __syncthreads();
  int c0 = cnt[2 * t], c1 = cnt[2 * t + 1];
  int s = c0 + c1;
  scan[t] = s;
  __syncthreads();
  for (int off = 1; off < 256; off <<= 1) {
    int u = (t >= off) ? scan[t - off] : 0;
    __syncthreads();
    scan[t] += u;
    __syncthreads();
  }
  int eb2 = scan[t] - s;
  sbase[2 * t] = eb2;
  sbase[2 * t + 1] = eb2 + c0;
  int g0 = b * 512 + 2 * t, g1 = g0 + 1;
  if (g0 < NN) {
    offs[g0] = base0 + eb2;
    inv[g0] = 1.0f / (float)(c0 > 1 ? c0 : 1);
  }
  if (g1 < NN) {
    offs[g1] = base0 + eb2 + c0;
    inv[g1] = 1.0f / (float)(c1 > 1 ? c1 : 1);
  }
  if (b == NBUCK - 1 && t == 0) offs[NN] = NE;
  cnt[2 * t] = 0; cnt[2 * t + 1] = 0;
  __syncthreads();
  for (int i = t; i < n; i += 256) {
    int2 e = eb[i];
    int ln = e.y & 511;
    int p = sbase[ln] + atomicAdd(&cnt[ln], 1);
    sarr[p] = e.x;
  }
  __syncthreads();
  for (int i = t; i < n; i += 256) ss[base0 + i] = sarr[i];
}

// Fused SAGE layer: block owns 128 dst rows.
// Phase 1: mean-gather -> hN tile in LDS (XOR-swizzled rows).
// Phase 2: relu([hIn | hN] @ W + bias) -> hOut bf16 (or outF f32 on last layer).
__global__ __launch_bounds__(256) void k_fused(
    const ushort* __restrict__ hIn, const int* __restrict__ offs,
    const int* __restrict__ ss, const float* __restrict__ inv_deg,
    const ushort* __restrict__ WtP, const float* __restrict__ bias,
    ushort* __restrict__ hOut, float* __restrict__ outF, int writeF) {
  __shared__ ushort hN[128 * 128];   // 32 KB, row stride 256B, byte ^= (row&7)<<4
  int t = threadIdx.x;
  int w = t >> 6, lane = t & 63;
  int r = lane & 15, kg = lane >> 4;
  int row0 = blockIdx.x * 128;

  // B fragments in registers (whole block's K, this wave's 32-col quarter)
  int colbase = w * 32;
  short8 bfrag[8][2];
#pragma unroll
  for (int kt = 0; kt < 8; ++kt)
#pragma unroll
    for (int nt = 0; nt < 2; ++nt) {
      int col = colbase + nt * 16 + r;
      bfrag[kt][nt] = *(const short8*)(WtP + ((size_t)(kt * 128 + col) * 4 + kg) * 8);
    }
  float bv[2];
  bv[0] = bias[colbase + r];
  bv[1] = bias[colbase + 16 + r];

  // ---- Phase 1: aggregate (4 nodes per wave at a time, 8 groups) ----
  const ushort* hp = hIn + (size_t)r * 8;   // lane's 16B column chunk
#pragma unroll 1
  for (int g = 0; g < 8; ++g) {
    int lr = w * 32 + g * 4 + kg;           // local row 0..127
    int v = row0 + lr;
    float a0 = 0, a1 = 0, a2 = 0, a3 = 0, a4 = 0, a5 = 0, a6 = 0, a7 = 0;
    if (v < NN) {
      int beg = offs[v], end = offs[v + 1];
#define ACC8(u) { a0 += b2f((ushort)u.x); a1 += b2f((ushort)(u.x >> 16)); \
                  a2 += b2f((ushort)u.y); a3 += b2f((ushort)(u.y >> 16)); \
                  a4 += b2f((ushort)u.z); a5 += b2f((ushort)(u.z >> 16)); \
                  a6 += b2f((ushort)u.w); a7 += b2f((ushort)(u.w >> 16)); }
      int e = beg;
      for (; e + 7 < end; e += 8) {
        uint4 u0 = *(const uint4*)(hp + (size_t)ss[e + 0] * DD);
        uint4 u1 = *(const uint4*)(hp + (size_t)ss[e + 1] * DD);
        uint4 u2 = *(const uint4*)(hp + (size_t)ss[e + 2] * DD);
        uint4 u3 = *(const uint4*)(hp + (size_t)ss[e + 3] * DD);
        uint4 u4 = *(const uint4*)(hp + (size_t)ss[e + 4] * DD);
        uint4 u5 = *(const uint4*)(hp + (size_t)ss[e + 5] * DD);
        uint4 u6 = *(const uint4*)(hp + (size_t)ss[e + 6] * DD);
        uint4 u7 = *(const uint4*)(hp + (size_t)ss[e + 7] * DD);
        ACC8(u0) ACC8(u1) ACC8(u2) ACC8(u3) ACC8(u4) ACC8(u5) ACC8(u6) ACC8(u7)
      }
      for (; e < end; ++e) {
        uint4 u0 = *(const uint4*)(hp + (size_t)ss[e] * DD);
        ACC8(u0)
      }
#undef ACC8
      float sc = inv_deg[v];
      a0 *= sc; a1 *= sc; a2 *= sc; a3 *= sc;
      a4 *= sc; a5 *= sc; a6 *= sc; a7 *= sc;
    }
    uint4 p;
    p.x = (uint)f2b(a0) | ((uint)f2b(a1) << 16);
    p.y = (uint)f2b(a2) | ((uint)f2b(a3) << 16);
    p.z = (uint)f2b(a4) | ((uint)f2b(a5) << 16);
    p.w = (uint)f2b(a6) | ((uint)f2b(a7) << 16);
    *(uint4*)((char*)hN + lr * 256 + ((r * 16) ^ ((lr & 7) << 4))) = p;
  }
  __syncthreads();

  // ---- Phase 2: GEMM ----
  f32x4 acc[4][2][2];
#pragma unroll
  for (int it = 0; it < 4; ++it)
#pragma unroll
    for (int mt = 0; mt < 2; ++mt)
#pragma unroll
      for (int nt = 0; nt < 2; ++nt) acc[it][mt][nt] = (f32x4)0.f;

#pragma unroll
  for (int it = 0; it < 4; ++it) {
    int lr0 = it * 32 + r, lr1 = lr0 + 16;
    int ra0 = row0 + lr0; if (ra0 > NN - 1) ra0 = NN - 1;
    int ra1 = row0 + lr1; if (ra1 > NN - 1) ra1 = NN - 1;
#pragma unroll
    for (int kt = 0; kt < 8; ++kt) {
      short8 a0, a1;
      if (kt < 4) {
        int kk = kt * 32 + kg * 8;
        a0 = *(const short8*)(hIn + (size_t)ra0 * DD + kk);
        a1 = *(const short8*)(hIn + (size_t)ra1 * DD + kk);
      } else {
        int bo = (kt & 3) * 64 + kg * 16;
        a0 = *(const short8*)((char*)hN + lr0 * 256 + (bo ^ ((lr0 & 7) << 4)));
        a1 = *(const short8*)((char*)hN + lr1 * 256 + (bo ^ ((lr1 & 7) << 4)));
      }
      acc[it][0][0] = __builtin_amdgcn_mfma_f32_16x16x32_bf16(a0, bfrag[kt][0], acc[it][0][0], 0, 0, 0);
      acc[it][0][1] = __builtin_amdgcn_mfma_f32_16x16x32_bf16(a0, bfrag[kt][1], acc[it][0][1], 0, 0, 0);
      acc[it][1][0] = __builtin_amdgcn_mfma_f32_16x16x32_bf16(a1, bfrag[kt][0], acc[it][1][0], 0, 0, 0);
      acc[it][1][1] = __builtin_amdgcn_mfma_f32_16x16x32_bf16(a1, bfrag[kt][1], acc[it][1][1], 0, 0, 0);
    }
  }

#pragma unroll
  for (int it = 0; it < 4; ++it)
#pragma unroll
    for (int mt = 0; mt < 2; ++mt)
#pragma unroll
      for (int j = 0; j < 4; ++j) {
        int row = row0 + it * 32 + mt * 16 + kg * 4 + j;
        if (row < NN) {
#pragma unroll
          for (int nt = 0; nt < 2; ++nt) {
            float val = fmaxf(acc[it][mt][nt][j] + bv[nt], 0.f);
            int col = colbase + nt * 16 + r;
            if (writeF) outF[(size_t)row * DD + col] = val;
            else        hOut[(size_t)row * DD + col] = f2b(val);
          }
        }
      }
}

extern "C" void kernel_launch(void* const* d_in, const int* in_sizes, int n_in,
                              void* d_out, int out_size, void* d_ws, size_t ws_size,
                              hipStream_t stream) {
  const float* x    = (const float*)d_in[0];
  const float* Ws   = (const float*)d_in[1];
  const float* Wn   = (const float*)d_in[2];
  const float* bias = (const float*)d_in[3];
  const int*   src  = (const int*)d_in[4];
  const int*   dst  = (const int*)d_in[5];
  float* out = (float*)d_out;

  int* ws      = (int*)d_ws;
  int* gcur    = ws + OFF_GCUR;
  int* offs    = ws + OFF_OFFS;
  float* inv   = (float*)(ws + OFF_INV);
  ushort* WtP  = (ushort*)(ws + OFF_WT);
  int* ssorted = ws + OFF_SS;
  ushort* hB   = (ushort*)(ws + OFF_HB);
  ushort* hC   = (ushort*)(ws + OFF_HC);
  int2* ebuf   = (int2*)(ws + OFF_HC);    // dead after k_sort; hC reuses

  k_pre<<<12885, 256, 0, stream>>>(x, Ws, Wn, hB, WtP, gcur);
  k_bucket<<<(NE + 4095) / 4096, 256, 0, stream>>>(src, dst, gcur, ebuf);
  k_sort<<<NBUCK, 256, 0, stream>>>(ebuf, gcur, offs, inv, ssorted);

  const ushort* hcur = hB;
  ushort* hnext = hC;
  for (int l = 0; l < 3; ++l) {
    k_fused<<<(NN + 127) / 128, 256, 0, stream>>>(
        hcur, offs, ssorted, inv, WtP + (size_t)l * 8 * 128 * 32,
        bias + l * DD, hnext, out, l == 2 ? 1 : 0);
    const ushort* tmp = hnext;
    hnext = (ushort*)hcur;
    hcur = tmp;
  }
}

// Round 9
// 521.006 us; speedup vs baseline: 1.0936x; 1.0936x over previous
//
#include <hip/hip_runtime.h>

typedef __attribute__((ext_vector_type(8))) short short8;
typedef __attribute__((ext_vector_type(4))) float f32x4;

static constexpr int NN = 100000;
static constexpr int NE = 1600000;
static constexpr int DD = 128;
static constexpr int NBUCK = 196;     // 512 nodes per bucket (dst >> 9)
static constexpr int CAP = 9216;      // mean 8192 + ~11 sigma

// ws layout in 4-byte words (peak 58.6 MB, proven)
static constexpr int OFF_GCUR = 0;         // 256
static constexpr int OFF_OFFS = 512;       // NN+1
static constexpr int OFF_INV  = 100516;    // NN
static constexpr int OFF_WT   = 200520;    // 3*8*128*32 bf16 = 49152 words
static constexpr int OFF_SS   = 249680;    // NE
static constexpr int OFF_HB   = 1849680;   // NN*64 (h, bf16, in-place across layers)
static constexpr int OFF_HNB  = 8249680;   // NN*64 (h_neigh bf16; ebuf aliases)

__device__ inline ushort f2b(float f) {
  uint u = __builtin_bit_cast(uint, f);
  uint r = (u + 0x7fffu + ((u >> 16) & 1u)) >> 16;
  return (ushort)r;
}
__device__ inline float b2f(ushort b) {
  uint u = ((uint)b) << 16;
  return __builtin_bit_cast(float, u);
}

// Fused pre-pass: blocks [0,12500) x->bf16, [12500,12884) weight repack, [12884] zero gcur
__global__ __launch_bounds__(256) void k_pre(const float* __restrict__ x,
                                             const float* __restrict__ Ws,
                                             const float* __restrict__ Wn,
                                             ushort* __restrict__ hb,
                                             ushort* __restrict__ WtP,
                                             int* __restrict__ gcur) {
  int b = blockIdx.x, t = threadIdx.x;
  if (b < 12500) {
    int i = b * 256 + t;               // < 3,200,000 = NN*32
    float4 v = *(const float4*)(x + (size_t)i * 4);
    uint2 p;
    p.x = (uint)f2b(v.x) | ((uint)f2b(v.y) << 16);
    p.y = (uint)f2b(v.z) | ((uint)f2b(v.w) << 16);
    *(uint2*)(hb + (size_t)i * 4) = p;
  } else if (b < 12884) {
    // WtP[((l*8+kt)*128+col)*32 + kg*8 + j] = W[l][kt*32+kg*8+j][col]
    int i = (b - 12500) * 256 + t;     // < 98304 = 3*8*128*32
    int j = i & 7;
    int kg = (i >> 3) & 3;
    int col = (i >> 5) & 127;
    int kt = (i >> 12) & 7;
    int l = i >> 15;
    int k = kt * 32 + kg * 8 + j;
    float v = (k < 128) ? Ws[((size_t)l * 128 + k) * 128 + col]
                        : Wn[((size_t)l * 128 + (k - 128)) * 128 + col];
    WtP[i] = f2b(v);
  } else {
    gcur[t] = 0;
  }
}

// Pass 1: bucket edges by dst>>9 into fixed-stride regions of ebuf
__global__ __launch_bounds__(256) void k_bucket(const int* __restrict__ src,
                                                const int* __restrict__ dst,
                                                int* __restrict__ gcur,
                                                int2* __restrict__ ebuf) {
  __shared__ int cnt[NBUCK], base[NBUCK];
  int t = threadIdx.x;
  int b0 = blockIdx.x * 4096;
  if (t < NBUCK) cnt[t] = 0;
  __syncthreads();
  int dv[16], pv[16];
#pragma unroll
  for (int j = 0; j < 16; ++j) {
    int idx = b0 + j * 256 + t;
    if (idx < NE) {
      int d = dst[idx];
      dv[j] = d;
      pv[j] = atomicAdd(&cnt[d >> 9], 1);
    } else dv[j] = -1;
  }
  __syncthreads();
  if (t < NBUCK) base[t] = atomicAdd(&gcur[t], cnt[t]);
  __syncthreads();
#pragma unroll
  for (int j = 0; j < 16; ++j) {
    if (dv[j] >= 0) {
      int idx = b0 + j * 256 + t;
      int b = dv[j] >> 9;
      int2 pr; pr.x = src[idx]; pr.y = dv[j];
      ebuf[(size_t)b * CAP + base[b] + pv[j]] = pr;
    }
  }
}

// Pass 2 (fused, inline bucket-scan): hist -> offs/inv -> LDS counting sort -> streamed ss
__global__ __launch_bounds__(256) void k_sort(const int2* __restrict__ ebuf,
                                              const int* __restrict__ gcur,
                                              int* __restrict__ offs,
                                              float* __restrict__ inv,
                                              int* __restrict__ ss) {
  __shared__ int cnt[512];
  __shared__ int sbase[512];
  __shared__ int scan[256];
  __shared__ int sarr[CAP];
  int b = blockIdx.x, t = threadIdx.x;
  int gv = (t < NBUCK) ? gcur[t] : 0;
  scan[t] = gv;
  __syncthreads();
  for (int off = 1; off < 256; off <<= 1) {
    int u = (t >= off) ? scan[t - off] : 0;
    __syncthreads();
    scan[t] += u;
    __syncthreads();
  }
  int nB = gcur[b];
  int base0 = scan[b] - nB;
  int n = nB;
  cnt[t] = 0; cnt[t + 256] = 0;
  __syncthreads();
  const int2* eb = ebuf + (size_t)b * CAP;
  for (int i = t; i < n; i += 256) atomicAdd(&cnt[eb[i].y & 511], 1);
  __syncthreads();
  int c0 = cnt[2 * t], c1 = cnt[2 * t + 1];
  int s = c0 + c1;
  scan[t] = s;
  __syncthreads();
  for (int off = 1; off < 256; off <<= 1) {
    int u = (t >= off) ? scan[t - off] : 0;
    __syncthreads();
    scan[t] += u;
    __syncthreads();
  }
  int eb2 = scan[t] - s;
  sbase[2 * t] = eb2;
  sbase[2 * t + 1] = eb2 + c0;
  int g0 = b * 512 + 2 * t, g1 = g0 + 1;
  if (g0 < NN) {
    offs[g0] = base0 + eb2;
    inv[g0] = 1.0f / (float)(c0 > 1 ? c0 : 1);
  }
  if (g1 < NN) {
    offs[g1] = base0 + eb2 + c0;
    inv[g1] = 1.0f / (float)(c1 > 1 ? c1 : 1);
  }
  if (b == NBUCK - 1 && t == 0) offs[NN] = NE;
  cnt[2 * t] = 0; cnt[2 * t + 1] = 0;
  __syncthreads();
  for (int i = t; i < n; i += 256) {
    int2 e = eb[i];
    int ln = e.y & 511;
    int p = sbase[ln] + atomicAdd(&cnt[ln], 1);
    sarr[p] = e.x;
  }
  __syncthreads();
  for (int i = t; i < n; i += 256) ss[base0 + i] = sarr[i];
}

// 4 nodes per wave (16 lanes/row, uint4 = 8 bf16/lane), unroll 8, fp32 accumulate
__global__ __launch_bounds__(256) void k_agg3(const ushort* __restrict__ h,
                                              const int* __restrict__ offs,
                                              const int* __restrict__ ss,
                                              const float* __restrict__ inv_deg,
                                              ushort* __restrict__ hN) {
  int gid = blockIdx.x * blockDim.x + threadIdx.x;
  int wid = gid >> 6;
  int lane = threadIdx.x & 63;
  int q = lane >> 4, l16 = lane & 15;
  int v = wid * 4 + q;
  int beg = offs[v], end = offs[v + 1];
  float a0 = 0, a1 = 0, a2 = 0, a3 = 0, a4 = 0, a5 = 0, a6 = 0, a7 = 0;
  const ushort* hp = h + (size_t)l16 * 8;
#define ACC8(u) { a0 += b2f((ushort)u.x); a1 += b2f((ushort)(u.x >> 16)); \
                  a2 += b2f((ushort)u.y); a3 += b2f((ushort)(u.y >> 16)); \
                  a4 += b2f((ushort)u.z); a5 += b2f((ushort)(u.z >> 16)); \
                  a6 += b2f((ushort)u.w); a7 += b2f((ushort)(u.w >> 16)); }
  int e = beg;
  for (; e + 7 < end; e += 8) {
    uint4 u0 = *(const uint4*)(hp + (size_t)ss[e + 0] * DD);
    uint4 u1 = *(const uint4*)(hp + (size_t)ss[e + 1] * DD);
    uint4 u2 = *(const uint4*)(hp + (size_t)ss[e + 2] * DD);
    uint4 u3 = *(const uint4*)(hp + (size_t)ss[e + 3] * DD);
    uint4 u4 = *(const uint4*)(hp + (size_t)ss[e + 4] * DD);
    uint4 u5 = *(const uint4*)(hp + (size_t)ss[e + 5] * DD);
    uint4 u6 = *(const uint4*)(hp + (size_t)ss[e + 6] * DD);
    uint4 u7 = *(const uint4*)(hp + (size_t)ss[e + 7] * DD);
    ACC8(u0) ACC8(u1) ACC8(u2) ACC8(u3) ACC8(u4) ACC8(u5) ACC8(u6) ACC8(u7)
  }
  for (; e < end; ++e) {
    uint4 u0 = *(const uint4*)(hp + (size_t)ss[e] * DD);
    ACC8(u0)
  }
#undef ACC8
  float w = inv_deg[v];
  a0 *= w; a1 *= w; a2 *= w; a3 *= w; a4 *= w; a5 *= w; a6 *= w; a7 *= w;
  uint4 p;
  p.x = (uint)f2b(a0) | ((uint)f2b(a1) << 16);
  p.y = (uint)f2b(a2) | ((uint)f2b(a3) << 16);
  p.z = (uint)f2b(a4) | ((uint)f2b(a5) << 16);
  p.w = (uint)f2b(a6) | ((uint)f2b(a7) << 16);
  *(uint4*)(hN + (size_t)v * DD + l16 * 8) = p;
}

// h_out = relu([hA|hN] @ W + bias). 32 rows/block (NN/32=3125 blocks exactly),
// 4 waves = 4 col-quarters; B-fragments in registers; block reads only its own
// 32 rows -> in-place safe with one barrier between reads and writes.
__global__ __launch_bounds__(256) void k_gemm3(
    const ushort* __restrict__ hA, const ushort* __restrict__ hNb,
    const ushort* __restrict__ WtP, const float* __restrict__ bias,
    ushort* __restrict__ hOutB, float* __restrict__ outF, int writeF) {
  int w = threadIdx.x >> 6;
  int lane = threadIdx.x & 63;
  int r = lane & 15, kg = lane >> 4;
  int colbase = w * 32;
  int row0 = blockIdx.x * 32;

  short8 bfrag[8][2];
#pragma unroll
  for (int kt = 0; kt < 8; ++kt)
#pragma unroll
    for (int nt = 0; nt < 2; ++nt) {
      int col = colbase + nt * 16 + r;
      bfrag[kt][nt] = *(const short8*)(WtP + ((size_t)(kt * 128 + col) * 4 + kg) * 8);
    }
  float bv[2];
  bv[0] = bias[colbase + r];
  bv[1] = bias[colbase + 16 + r];

  int ra0 = row0 + r;
  int ra1 = row0 + 16 + r;

  f32x4 acc[2][2];
#pragma unroll
  for (int mt = 0; mt < 2; ++mt)
#pragma unroll
    for (int nt = 0; nt < 2; ++nt) acc[mt][nt] = (f32x4)0.f;

#pragma unroll
  for (int kt = 0; kt < 8; ++kt) {
    const ushort* hs = (kt < 4) ? hA : hNb;
    int kk = (kt & 3) * 32 + kg * 8;
    short8 a0 = *(const short8*)(hs + (size_t)ra0 * DD + kk);
    short8 a1 = *(const short8*)(hs + (size_t)ra1 * DD + kk);
    acc[0][0] = __builtin_amdgcn_mfma_f32_16x16x32_bf16(a0, bfrag[kt][0], acc[0][0], 0, 0, 0);
    acc[0][1] = __builtin_amdgcn_mfma_f32_16x16x32_bf16(a0, bfrag[kt][1], acc[0][1], 0, 0, 0);
    acc[1][0] = __builtin_amdgcn_mfma_f32_16x16x32_bf16(a1, bfrag[kt][0], acc[1][0], 0, 0, 0);
    acc[1][1] = __builtin_amdgcn_mfma_f32_16x16x32_bf16(a1, bfrag[kt][1], acc[1][1], 0, 0, 0);
  }

  __syncthreads();   // all reads of this block's 32 rows complete before any write

#pragma unroll
  for (int mt = 0; mt < 2; ++mt) {
#pragma unroll
    for (int j = 0; j < 4; ++j) {
      int row = row0 + mt * 16 + kg * 4 + j;
#pragma unroll
      for (int nt = 0; nt < 2; ++nt) {
        float val = fmaxf(acc[mt][nt][j] + bv[nt], 0.f);
        int col = colbase + nt * 16 + r;
        if (writeF) outF[(size_t)row * DD + col] = val;
        else        hOutB[(size_t)row * DD + col] = f2b(val);
      }
    }
  }
}

extern "C" void kernel_launch(void* const* d_in, const int* in_sizes, int n_in,
                              void* d_out, int out_size, void* d_ws, size_t ws_size,
                              hipStream_t stream) {
  const float* x    = (const float*)d_in[0];
  const float* Ws   = (const float*)d_in[1];
  const float* Wn   = (const float*)d_in[2];
  const float* bias = (const float*)d_in[3];
  const int*   src  = (const int*)d_in[4];
  const int*   dst  = (const int*)d_in[5];
  float* out = (float*)d_out;

  int* ws      = (int*)d_ws;
  int* gcur    = ws + OFF_GCUR;
  int* offs    = ws + OFF_OFFS;
  float* inv   = (float*)(ws + OFF_INV);
  ushort* WtP  = (ushort*)(ws + OFF_WT);
  int* ssorted = ws + OFF_SS;
  ushort* hB   = (ushort*)(ws + OFF_HB);
  ushort* hNb  = (ushort*)(ws + OFF_HNB);
  int2* ebuf   = (int2*)(ws + OFF_HNB);   // dead after k_sort; hNb reuses

  k_pre<<<12885, 256, 0, stream>>>(x, Ws, Wn, hB, WtP, gcur);
  k_bucket<<<(NE + 4095) / 4096, 256, 0, stream>>>(src, dst, gcur, ebuf);
  k_sort<<<NBUCK, 256, 0, stream>>>(ebuf, gcur, offs, inv, ssorted);

  // 3 SAGE layers; h stays in hB (in-place GEMM), last layer writes f32 out
  for (int l = 0; l < 3; ++l) {
    k_agg3<<<NN / 16, 256, 0, stream>>>(hB, offs, ssorted, inv, hNb);
    k_gemm3<<<NN / 32, 256, 0, stream>>>(
        hB, hNb, WtP + (size_t)l * 8 * 128 * 32, bias + l * DD, hB, out, l == 2 ? 1 : 0);
  }
}

// Round 10
// 505.483 us; speedup vs baseline: 1.1272x; 1.0307x over previous
//
#include <hip/hip_runtime.h>

typedef __attribute__((ext_vector_type(8))) short short8;
typedef __attribute__((ext_vector_type(4))) float f32x4;

static constexpr int NN = 100000;
static constexpr int NE = 1600000;
static constexpr int DD = 128;
static constexpr int NBUCK = 196;     // 512 nodes per bucket (dst >> 9)
static constexpr int CAP = 9216;      // mean 8192 + ~11 sigma

// ws layout in 4-byte words (peak 58.6 MB)
static constexpr int OFF_GCUR = 0;         // 256
static constexpr int OFF_OFFS = 512;       // NN+1
static constexpr int OFF_INV  = 100516;    // NN
static constexpr int OFF_WT   = 200520;    // 3*8*128*32 bf16 = 49152 words
static constexpr int OFF_SS   = 249680;    // NE
static constexpr int OFF_HB   = 1849680;   // NN*64 (h, bf16, in-place across layers)
static constexpr int OFF_HNB  = 8249680;   // NN*64 (h_neigh bf16; ebuf aliases)

__device__ inline ushort f2b(float f) {
  uint u = __builtin_bit_cast(uint, f);
  uint r = (u + 0x7fffu + ((u >> 16) & 1u)) >> 16;
  return (ushort)r;
}
__device__ inline float b2f(ushort b) {
  uint u = ((uint)b) << 16;
  return __builtin_bit_cast(float, u);
}

// Fused pre-pass: blocks [0,12500) x->bf16, [12500,12884) weight repack, [12884] zero gcur
__global__ __launch_bounds__(256) void k_pre(const float* __restrict__ x,
                                             const float* __restrict__ Ws,
                                             const float* __restrict__ Wn,
                                             ushort* __restrict__ hb,
                                             ushort* __restrict__ WtP,
                                             int* __restrict__ gcur) {
  int b = blockIdx.x, t = threadIdx.x;
  if (b < 12500) {
    int i = b * 256 + t;               // < 3,200,000 = NN*32
    float4 v = *(const float4*)(x + (size_t)i * 4);
    uint2 p;
    p.x = (uint)f2b(v.x) | ((uint)f2b(v.y) << 16);
    p.y = (uint)f2b(v.z) | ((uint)f2b(v.w) << 16);
    *(uint2*)(hb + (size_t)i * 4) = p;
  } else if (b < 12884) {
    // WtP[((l*8+kt)*128+col)*32 + kg*8 + j] = W[l][kt*32+kg*8+j][col]
    int i = (b - 12500) * 256 + t;     // < 98304 = 3*8*128*32
    int j = i & 7;
    int kg = (i >> 3) & 3;
    int col = (i >> 5) & 127;
    int kt = (i >> 12) & 7;
    int l = i >> 15;
    int k = kt * 32 + kg * 8 + j;
    float v = (k < 128) ? Ws[((size_t)l * 128 + k) * 128 + col]
                        : Wn[((size_t)l * 128 + (k - 128)) * 128 + col];
    WtP[i] = f2b(v);
  } else {
    gcur[t] = 0;
  }
}

// Pass 1: bucket edges by dst>>9; packed entry = (dst&511)<<17 | src  (26 bits)
__global__ __launch_bounds__(512) void k_bucket(const int* __restrict__ src,
                                                const int* __restrict__ dst,
                                                int* __restrict__ gcur,
                                                int* __restrict__ ebuf) {
  __shared__ int cnt[2][NBUCK];
  __shared__ int base[NBUCK];
  int t = threadIdx.x;
  int b0 = blockIdx.x * 4096;
  int half = t & 1;
  if (t < NBUCK) { cnt[0][t] = 0; cnt[1][t] = 0; }
  __syncthreads();
  int dv[8], pv[8];
#pragma unroll
  for (int j = 0; j < 8; ++j) {
    int idx = b0 + j * 512 + t;
    if (idx < NE) {
      int d = dst[idx];
      dv[j] = d;
      pv[j] = atomicAdd(&cnt[half][d >> 9], 1);
    } else dv[j] = -1;
  }
  __syncthreads();
  if (t < NBUCK) base[t] = atomicAdd(&gcur[t], cnt[0][t] + cnt[1][t]);
  __syncthreads();
#pragma unroll
  for (int j = 0; j < 8; ++j) {
    if (dv[j] >= 0) {
      int idx = b0 + j * 512 + t;
      int b = dv[j] >> 9;
      int pos = pv[j] + (half ? cnt[0][b] : 0);   // odd-half entries after even-half
      ebuf[(size_t)b * CAP + base[b] + pos] = ((dv[j] & 511) << 17) | src[idx];
    }
  }
}

// Pass 2 (fused, inline bucket-scan): hist -> offs/inv -> LDS counting sort -> streamed ss
__global__ __launch_bounds__(512) void k_sort(const int* __restrict__ ebuf,
                                              const int* __restrict__ gcur,
                                              int* __restrict__ offs,
                                              float* __restrict__ inv,
                                              int* __restrict__ ss) {
  __shared__ int cnt[512];
  __shared__ int sbase[512];
  __shared__ int scan[256];
  __shared__ int sarr[CAP];
  int b = blockIdx.x, t = threadIdx.x;
  // inline exclusive scan of gcur over buckets (threads 0..255 participate)
  if (t < 256) {
    int gv = (t < NBUCK) ? gcur[t] : 0;
    scan[t] = gv;
  }
  __syncthreads();
  for (int off = 1; off < 256; off <<= 1) {
    int u = (t < 256 && t >= off) ? scan[t - off] : 0;
    __syncthreads();
    if (t < 256) scan[t] += u;
    __syncthreads();
  }
  int nB = gcur[b];
  int base0 = scan[b] - nB;
  int n = nB;
  cnt[t] = 0;
  __syncthreads();
  const int* eb = ebuf + (size_t)b * CAP;
  for (int i = t; i < n; i += 512) atomicAdd(&cnt[(eb[i] >> 17) & 511], 1);
  __syncthreads();
  int c0 = 0, c1 = 0, s = 0;
  if (t < 256) {
    c0 = cnt[2 * t]; c1 = cnt[2 * t + 1];
    s = c0 + c1;
    scan[t] = s;
  }
  __syncthreads();
  for (int off = 1; off < 256; off <<= 1) {
    int u = (t < 256 && t >= off) ? scan[t - off] : 0;
    __syncthreads();
    if (t < 256) scan[t] += u;
    __syncthreads();
  }
  if (t < 256) {
    int eb2 = scan[t] - s;
    sbase[2 * t] = eb2;
    sbase[2 * t + 1] = eb2 + c0;
    int g0 = b * 512 + 2 * t, g1 = g0 + 1;
    if (g0 < NN) {
      offs[g0] = base0 + eb2;
      inv[g0] = 1.0f / (float)(c0 > 1 ? c0 : 1);
    }
    if (g1 < NN) {
      offs[g1] = base0 + eb2 + c0;
      inv[g1] = 1.0f / (float)(c1 > 1 ? c1 : 1);
    }
  }
  if (b == NBUCK - 1 && t == 0) offs[NN] = NE;
  __syncthreads();
  cnt[t] = 0;
  __syncthreads();
  for (int i = t; i < n; i += 512) {
    int e = eb[i];
    int ln = (e >> 17) & 511;
    int p = sbase[ln] + atomicAdd(&cnt[ln], 1);
    sarr[p] = e & 131071;
  }
  __syncthreads();
  for (int i = t; i < n; i += 512) ss[base0 + i] = sarr[i];
}

// 4 nodes per wave (16 lanes/row, uint4 = 8 bf16/lane), unroll 8, fp32 accumulate
__global__ __launch_bounds__(256) void k_agg3(const ushort* __restrict__ h,
                                              const int* __restrict__ offs,
                                              const int* __restrict__ ss,
                                              const float* __restrict__ inv_deg,
                                              ushort* __restrict__ hN) {
  int gid = blockIdx.x * blockDim.x + threadIdx.x;
  int wid = gid >> 6;
  int lane = threadIdx.x & 63;
  int q = lane >> 4, l16 = lane & 15;
  int v = wid * 4 + q;
  int beg = offs[v], end = offs[v + 1];
  float a0 = 0, a1 = 0, a2 = 0, a3 = 0, a4 = 0, a5 = 0, a6 = 0, a7 = 0;
  const ushort* hp = h + (size_t)l16 * 8;
#define ACC8(u) { a0 += b2f((ushort)u.x); a1 += b2f((ushort)(u.x >> 16)); \
                  a2 += b2f((ushort)u.y); a3 += b2f((ushort)(u.y >> 16)); \
                  a4 += b2f((ushort)u.z); a5 += b2f((ushort)(u.z >> 16)); \
                  a6 += b2f((ushort)u.w); a7 += b2f((ushort)(u.w >> 16)); }
  int e = beg;
  for (; e + 7 < end; e += 8) {
    uint4 u0 = *(const uint4*)(hp + (size_t)ss[e + 0] * DD);
    uint4 u1 = *(const uint4*)(hp + (size_t)ss[e + 1] * DD);
    uint4 u2 = *(const uint4*)(hp + (size_t)ss[e + 2] * DD);
    uint4 u3 = *(const uint4*)(hp + (size_t)ss[e + 3] * DD);
    uint4 u4 = *(const uint4*)(hp + (size_t)ss[e + 4] * DD);
    uint4 u5 = *(const uint4*)(hp + (size_t)ss[e + 5] * DD);
    uint4 u6 = *(const uint4*)(hp + (size_t)ss[e + 6] * DD);
    uint4 u7 = *(const uint4*)(hp + (size_t)ss[e + 7] * DD);
    ACC8(u0) ACC8(u1) ACC8(u2) ACC8(u3) ACC8(u4) ACC8(u5) ACC8(u6) ACC8(u7)
  }
  for (; e < end; ++e) {
    uint4 u0 = *(const uint4*)(hp + (size_t)ss[e] * DD);
    ACC8(u0)
  }
#undef ACC8
  float w = inv_deg[v];
  a0 *= w; a1 *= w; a2 *= w; a3 *= w; a4 *= w; a5 *= w; a6 *= w; a7 *= w;
  uint4 p;
  p.x = (uint)f2b(a0) | ((uint)f2b(a1) << 16);
  p.y = (uint)f2b(a2) | ((uint)f2b(a3) << 16);
  p.z = (uint)f2b(a4) | ((uint)f2b(a5) << 16);
  p.w = (uint)f2b(a6) | ((uint)f2b(a7) << 16);
  *(uint4*)(hN + (size_t)v * DD + l16 * 8) = p;
}

// h_out = relu([hA|hN] @ W + bias). 32 rows/block (NN/32=3125 blocks exactly),
// 4 waves = 4 col-quarters; B-fragments in registers; block reads only its own
// 32 rows -> in-place safe with one barrier between reads and writes.
__global__ __launch_bounds__(256) void k_gemm3(
    const ushort* __restrict__ hA, const ushort* __restrict__ hNb,
    const ushort* __restrict__ WtP, const float* __restrict__ bias,
    ushort* __restrict__ hOutB, float* __restrict__ outF, int writeF) {
  int w = threadIdx.x >> 6;
  int lane = threadIdx.x & 63;
  int r = lane & 15, kg = lane >> 4;
  int colbase = w * 32;
  int row0 = blockIdx.x * 32;

  short8 bfrag[8][2];
#pragma unroll
  for (int kt = 0; kt < 8; ++kt)
#pragma unroll
    for (int nt = 0; nt < 2; ++nt) {
      int col = colbase + nt * 16 + r;
      bfrag[kt][nt] = *(const short8*)(WtP + ((size_t)(kt * 128 + col) * 4 + kg) * 8);
    }
  float bv[2];
  bv[0] = bias[colbase + r];
  bv[1] = bias[colbase + 16 + r];

  int ra0 = row0 + r;
  int ra1 = row0 + 16 + r;

  f32x4 acc[2][2];
#pragma unroll
  for (int mt = 0; mt < 2; ++mt)
#pragma unroll
    for (int nt = 0; nt < 2; ++nt) acc[mt][nt] = (f32x4)0.f;

#pragma unroll
  for (int kt = 0; kt < 8; ++kt) {
    const ushort* hs = (kt < 4) ? hA : hNb;
    int kk = (kt & 3) * 32 + kg * 8;
    short8 a0 = *(const short8*)(hs + (size_t)ra0 * DD + kk);
    short8 a1 = *(const short8*)(hs + (size_t)ra1 * DD + kk);
    acc[0][0] = __builtin_amdgcn_mfma_f32_16x16x32_bf16(a0, bfrag[kt][0], acc[0][0], 0, 0, 0);
    acc[0][1] = __builtin_amdgcn_mfma_f32_16x16x32_bf16(a0, bfrag[kt][1], acc[0][1], 0, 0, 0);
    acc[1][0] = __builtin_amdgcn_mfma_f32_16x16x32_bf16(a1, bfrag[kt][0], acc[1][0], 0, 0, 0);
    acc[1][1] = __builtin_amdgcn_mfma_f32_16x16x32_bf16(a1, bfrag[kt][1], acc[1][1], 0, 0, 0);
  }

  __syncthreads();   // all reads of this block's 32 rows complete before any write

#pragma unroll
  for (int mt = 0; mt < 2; ++mt) {
#pragma unroll
    for (int j = 0; j < 4; ++j) {
      int row = row0 + mt * 16 + kg * 4 + j;
#pragma unroll
      for (int nt = 0; nt < 2; ++nt) {
        float val = fmaxf(acc[mt][nt][j] + bv[nt], 0.f);
        int col = colbase + nt * 16 + r;
        if (writeF) outF[(size_t)row * DD + col] = val;
        else        hOutB[(size_t)row * DD + col] = f2b(val);
      }
    }
  }
}

extern "C" void kernel_launch(void* const* d_in, const int* in_sizes, int n_in,
                              void* d_out, int out_size, void* d_ws, size_t ws_size,
                              hipStream_t stream) {
  const float* x    = (const float*)d_in[0];
  const float* Ws   = (const float*)d_in[1];
  const float* Wn   = (const float*)d_in[2];
  const float* bias = (const float*)d_in[3];
  const int*   src  = (const int*)d_in[4];
  const int*   dst  = (const int*)d_in[5];
  float* out = (float*)d_out;

  int* ws      = (int*)d_ws;
  int* gcur    = ws + OFF_GCUR;
  int* offs    = ws + OFF_OFFS;
  float* inv   = (float*)(ws + OFF_INV);
  ushort* WtP  = (ushort*)(ws + OFF_WT);
  int* ssorted = ws + OFF_SS;
  ushort* hB   = (ushort*)(ws + OFF_HB);
  ushort* hNb  = (ushort*)(ws + OFF_HNB);
  int* ebuf    = ws + OFF_HNB;            // dead after k_sort; hNb reuses

  k_pre<<<12885, 256, 0, stream>>>(x, Ws, Wn, hB, WtP, gcur);
  k_bucket<<<(NE + 4095) / 4096, 512, 0, stream>>>(src, dst, gcur, ebuf);
  k_sort<<<NBUCK, 512, 0, stream>>>(ebuf, gcur, offs, inv, ssorted);

  // 3 SAGE layers; h stays in hB (in-place GEMM), last layer writes f32 out
  for (int l = 0; l < 3; ++l) {
    k_agg3<<<NN / 16, 256, 0, stream>>>(hB, offs, ssorted, inv, hNb);
    k_gemm3<<<NN / 32, 256, 0, stream>>>(
        hB, hNb, WtP + (size_t)l * 8 * 128 * 32, bias + l * DD, hB, out, l == 2 ? 1 : 0);
  }
}